// Round 1
// baseline (2840.436 us; speedup 1.0000x reference)
//
#include <hip/hip_runtime.h>
#include <hip/hip_bf16.h>

// Sizes (fixed for this problem)
//   T=512 tokens, D=256 embed, L=256 lstm, H=512 hidden. 4L = 1024.

typedef _Float16 h2v __attribute__((ext_vector_type(2)));

__device__ __forceinline__ float fdot2f(h2v a, h2v b, float c) {
#if __has_builtin(__builtin_amdgcn_fdot2)
    return __builtin_amdgcn_fdot2(a, b, c, false);
#else
    return c + (float)a[0] * (float)b[0] + (float)a[1] * (float)b[1];
#endif
}

// ---------------------------------------------------------------------------
// prep_u: convert U [256 x 1024] f32 row-major -> packed half2 per (k-pair, col)
// layout: Uf[k2*1024 + col] = (U[2k2][col], U[2k2+1][col]) as 2xf16 in a uint
// ---------------------------------------------------------------------------
__global__ __launch_bounds__(256) void prep_u(const float* __restrict__ U,
                                              unsigned int* __restrict__ Uf) {
    int idx = blockIdx.x * 256 + threadIdx.x;  // < 131072
    int k2 = idx >> 10, col = idx & 1023;
    union { _Float16 h[2]; unsigned int u; } p;
    p.h[0] = (_Float16)U[(2 * k2) * 1024 + col];
    p.h[1] = (_Float16)U[(2 * k2 + 1) * 1024 + col];
    Uf[idx] = p.u;
}

// ---------------------------------------------------------------------------
// Generic f32 GEMM: C[M,N] = opA(A)[M,K] @ B[K,N] + bias[N]
// opA = optional row reversal (revA). 64x64 tile, 256 threads, 4x4 microtile.
// All dims are multiples of 64/16 here, no bounds checks.
// ---------------------------------------------------------------------------
__global__ __launch_bounds__(256) void gemm_bias(const float* __restrict__ A,
                                                 const float* __restrict__ B,
                                                 const float* __restrict__ bias,
                                                 float* __restrict__ C,
                                                 int M, int N, int K, int revA) {
    __shared__ float sA[16][65];
    __shared__ float sB[16][65];
    int tid = threadIdx.x;
    int bm = blockIdx.y * 64, bn = blockIdx.x * 64;
    int tx = tid & 15, ty = tid >> 4;
    float acc[4][4] = {};
    for (int k0 = 0; k0 < K; k0 += 16) {
#pragma unroll
        for (int l = 0; l < 4; l++) {
            int flat = tid + 256 * l;        // 0..1023 = 64 rows x 16 k
            int ml = flat >> 4, kk = flat & 15;
            int row = bm + ml;
            if (revA) row = M - 1 - row;
            sA[kk][ml] = A[row * K + k0 + kk];
        }
#pragma unroll
        for (int l = 0; l < 4; l++) {
            int flat = tid + 256 * l;        // 16 k x 64 n
            int kk = flat >> 6, nl = flat & 63;
            sB[kk][nl] = B[(k0 + kk) * N + bn + nl];
        }
        __syncthreads();
#pragma unroll
        for (int kk = 0; kk < 16; kk++) {
            float a[4], b[4];
#pragma unroll
            for (int i = 0; i < 4; i++) a[i] = sA[kk][ty + 16 * i];
#pragma unroll
            for (int j = 0; j < 4; j++) b[j] = sB[kk][tx + 16 * j];
#pragma unroll
            for (int i = 0; i < 4; i++)
#pragma unroll
                for (int j = 0; j < 4; j++) acc[i][j] += a[i] * b[j];
        }
        __syncthreads();
    }
#pragma unroll
    for (int i = 0; i < 4; i++) {
        int r = bm + ty + 16 * i;
#pragma unroll
        for (int j = 0; j < 4; j++) {
            int cidx = bn + tx + 16 * j;
            float bv = bias ? bias[cidx] : 0.f;
            C[r * N + cidx] = acc[i][j] + bv;
        }
    }
}

// ---------------------------------------------------------------------------
// lstm_two: 2 blocks (fwd, bwd), 512 threads each, 1 CU per block.
// U (f16 packed) resident: k2 in [0,36) in LDS (144KB), k2 in [36,128) in
// 184 VGPRs/thread (2 columns x 92 half2). h carried as f16 in LDS,
// c as f32 in registers of threads 0..255. P = pre-gates [512][1024] f32.
// Gate order i,f,g,o in the 1024 columns.
// ---------------------------------------------------------------------------
#define KLDS 36
#define KREG 92

__global__ __launch_bounds__(512, 2) void lstm_two(
        const unsigned int* __restrict__ Ua, const unsigned int* __restrict__ Ub,
        const float* __restrict__ Pa, const float* __restrict__ Pb,
        float* __restrict__ Oa, float* __restrict__ Ob) {
    const unsigned int* U = blockIdx.x ? Ub : Ua;
    const float* P = blockIdx.x ? Pb : Pa;
    float* O = blockIdx.x ? Ob : Oa;

    __shared__ unsigned int sU[KLDS * 1024];        // 147456 B
    __shared__ __align__(16) _Float16 sH[256];      // 512 B
    __shared__ float sZ[1024];                      // 4096 B

    int t = threadIdx.x;  // 0..511, owns columns 2t and 2t+1

    // stage LDS-resident part of U
    for (int i = t; i < KLDS * 1024; i += 512) sU[i] = U[i];

    // register-resident part of U
    unsigned int ur0[KREG], ur1[KREG];
#pragma unroll
    for (int r = 0; r < KREG; r++) {
        ur0[r] = U[(KLDS + r) * 1024 + 2 * t];
        ur1[r] = U[(KLDS + r) * 1024 + 2 * t + 1];
    }

    float c = 0.f;
    if (t < 256) sH[t] = (_Float16)0.f;
    __syncthreads();

    float2 pc = *(const float2*)(P + 2 * t);
    for (int step = 0; step < 512; step++) {
        float2 pn = pc;
        if (step < 511) pn = *(const float2*)(P + (step + 1) * 1024 + 2 * t);
        float acc0 = pc.x, acc1 = pc.y;
        const h2v* hp = (const h2v*)sH;
#pragma unroll
        for (int k2 = 0; k2 < KLDS; k2++) {
            h2v h = hp[k2];
            unsigned int u0 = sU[k2 * 1024 + 2 * t];
            unsigned int u1 = sU[k2 * 1024 + 2 * t + 1];
            acc0 = fdot2f(h, __builtin_bit_cast(h2v, u0), acc0);
            acc1 = fdot2f(h, __builtin_bit_cast(h2v, u1), acc1);
        }
#pragma unroll
        for (int r = 0; r < KREG; r++) {
            h2v h = hp[KLDS + r];
            acc0 = fdot2f(h, __builtin_bit_cast(h2v, ur0[r]), acc0);
            acc1 = fdot2f(h, __builtin_bit_cast(h2v, ur1[r]), acc1);
        }
        sZ[2 * t] = acc0;
        sZ[2 * t + 1] = acc1;
        __syncthreads();
        if (t < 256) {
            float zi = sZ[t], zf = sZ[256 + t], zg = sZ[512 + t], zo = sZ[768 + t];
            float ig = 1.f / (1.f + __expf(-zi));
            float fg = 1.f / (1.f + __expf(-zf));
            float gg = 1.f - 2.f / (1.f + __expf(2.f * zg));   // tanh
            float og = 1.f / (1.f + __expf(-zo));
            c = fg * c + ig * gg;
            float h = og * (1.f - 2.f / (1.f + __expf(2.f * c)));
            O[step * 256 + t] = h;
            sH[t] = (_Float16)h;
        }
        __syncthreads();
        pc = pn;
    }
}

// ---------------------------------------------------------------------------
// concat: V[t][0:256] = F[t], V[t][256:512] = Bk[511-t]
// ---------------------------------------------------------------------------
__global__ __launch_bounds__(256) void concat_k(const float* __restrict__ F,
                                                const float* __restrict__ Bk,
                                                float* __restrict__ V) {
    int idx = blockIdx.x * 256 + threadIdx.x;  // < 262144
    int t = idx >> 9, d = idx & 511;
    V[idx] = (d < 256) ? F[t * 256 + d] : Bk[(511 - t) * 256 + d - 256];
}

// ---------------------------------------------------------------------------
// head: S[i][j] = sum_h tanh(HF[i][h] + MF[j][h]) * w[h] + outBias
// (hidBias already folded into HF by its GEMM.)
// 1 block per i; 4 waves stride over j; 64 lanes reduce the 512-dim h.
// ---------------------------------------------------------------------------
__global__ __launch_bounds__(256) void head_kernel(const float* __restrict__ HF,
                                                   const float* __restrict__ MF,
                                                   const float* __restrict__ w,
                                                   const float* __restrict__ outb,
                                                   float* __restrict__ S) {
    int i = blockIdx.x;
    __shared__ float sHF[512], sW[512];
    int tid = threadIdx.x;
    sHF[tid] = HF[i * 512 + tid];
    sHF[tid + 256] = HF[i * 512 + 256 + tid];
    sW[tid] = w[tid];
    sW[tid + 256] = w[tid + 256];
    __syncthreads();
    int lane = tid & 63, wv = tid >> 6;
    float ob = outb[0];
    for (int j = wv; j < 512; j += 4) {
        const float* mf = MF + j * 512;
        float acc = 0.f;
#pragma unroll
        for (int r = 0; r < 8; r++) {
            int h = lane + 64 * r;
            float x = sHF[h] + mf[h];
            acc += sW[h] * (1.f - 2.f / (1.f + __expf(2.f * x)));
        }
#pragma unroll
        for (int off = 32; off; off >>= 1) acc += __shfl_down(acc, off);
        if (lane == 0) S[i * 512 + j] = acc + ob;
    }
}

// ---------------------------------------------------------------------------
extern "C" void kernel_launch(void* const* d_in, const int* in_sizes, int n_in,
                              void* d_out, int out_size, void* d_ws, size_t ws_size,
                              hipStream_t stream) {
    const float* emb      = (const float*)d_in[0];
    const float* W_f1     = (const float*)d_in[1];
    const float* U_f1     = (const float*)d_in[2];
    const float* b_f1     = (const float*)d_in[3];
    const float* W_b1     = (const float*)d_in[4];
    const float* U_b1     = (const float*)d_in[5];
    const float* b_b1     = (const float*)d_in[6];
    const float* W_f2     = (const float*)d_in[7];
    const float* U_f2     = (const float*)d_in[8];
    const float* b_f2     = (const float*)d_in[9];
    const float* W_b2     = (const float*)d_in[10];
    const float* U_b2     = (const float*)d_in[11];
    const float* b_b2     = (const float*)d_in[12];
    const float* FOH      = (const float*)d_in[13];
    const float* FOM      = (const float*)d_in[14];
    const float* hidBias  = (const float*)d_in[15];
    const float* outLayer = (const float*)d_in[16];
    const float* outBias  = (const float*)d_in[17];
    float* out = (float*)d_out;

    // workspace carve (16 MB total)
    unsigned int* uf = (unsigned int*)d_ws;          // 4 x 131072 uints = 2MB
    unsigned int* uf_f1 = uf;
    unsigned int* uf_b1 = uf + 131072;
    unsigned int* uf_f2 = uf + 262144;
    unsigned int* uf_b2 = uf + 393216;
    float* f = (float*)d_ws + 524288;
    float* P1f = f;                 // 512x1024
    float* P1b = f + 524288;
    float* P2f = f + 1048576;
    float* P2b = f + 1572864;
    float* rf1 = f + 2097152;       // 512x256
    float* rb1 = f + 2228224;
    float* rf2 = f + 2359296;
    float* rb2 = f + 2490368;
    float* v    = f + 2621440;      // 512x512
    float* hcat = f + 2883584;
    float* HFb  = f + 3145728;      // 512x512 (includes hidBias)
    float* MFb  = f + 3407872;

    prep_u<<<512, 256, 0, stream>>>(U_f1, uf_f1);
    prep_u<<<512, 256, 0, stream>>>(U_b1, uf_b1);
    prep_u<<<512, 256, 0, stream>>>(U_f2, uf_f2);
    prep_u<<<512, 256, 0, stream>>>(U_b2, uf_b2);

    dim3 g1(1024 / 64, 512 / 64);
    gemm_bias<<<g1, 256, 0, stream>>>(emb, W_f1, b_f1, P1f, 512, 1024, 256, 0);
    gemm_bias<<<g1, 256, 0, stream>>>(emb, W_b1, b_b1, P1b, 512, 1024, 256, 1);

    lstm_two<<<2, 512, 0, stream>>>(uf_f1, uf_b1, P1f, P1b, rf1, rb1);

    concat_k<<<1024, 256, 0, stream>>>(rf1, rb1, v);

    gemm_bias<<<g1, 256, 0, stream>>>(v, W_f2, b_f2, P2f, 512, 1024, 512, 0);
    gemm_bias<<<g1, 256, 0, stream>>>(v, W_b2, b_b2, P2b, 512, 1024, 512, 1);

    lstm_two<<<2, 512, 0, stream>>>(uf_f2, uf_b2, P2f, P2b, rf2, rb2);

    concat_k<<<1024, 256, 0, stream>>>(rf2, rb2, hcat);

    dim3 g2(512 / 64, 512 / 64);
    gemm_bias<<<g2, 256, 0, stream>>>(hcat, FOH, hidBias, HFb, 512, 512, 512, 0);
    gemm_bias<<<g2, 256, 0, stream>>>(hcat, FOM, nullptr, MFb, 512, 512, 512, 0);

    head_kernel<<<512, 256, 0, stream>>>(HFb, MFb, outLayer, outBias, out);
}

// Round 2
// 2817.054 us; speedup vs baseline: 1.0083x; 1.0083x over previous
//
#include <hip/hip_runtime.h>
#include <hip/hip_bf16.h>

// Sizes (fixed for this problem)
//   T=512 tokens, D=256 embed, L=256 lstm, H=512 hidden. 4L = 1024.

typedef _Float16 h2v __attribute__((ext_vector_type(2)));

__device__ __forceinline__ float fdot2f(h2v a, h2v b, float c) {
#if __has_builtin(__builtin_amdgcn_fdot2)
    return __builtin_amdgcn_fdot2(a, b, c, false);
#else
    return c + (float)a[0] * (float)b[0] + (float)a[1] * (float)b[1];
#endif
}

// ---------------------------------------------------------------------------
// prep_u: convert U [256 x 1024] f32 row-major -> packed half2 per (k-pair, col)
// layout: Uf[k2*1024 + col] = (U[2k2][col], U[2k2+1][col]) as 2xf16 in a uint
// ---------------------------------------------------------------------------
__global__ __launch_bounds__(256) void prep_u(const float* __restrict__ U,
                                              unsigned int* __restrict__ Uf) {
    int idx = blockIdx.x * 256 + threadIdx.x;  // < 131072
    int k2 = idx >> 10, col = idx & 1023;
    union { _Float16 h[2]; unsigned int u; } p;
    p.h[0] = (_Float16)U[(2 * k2) * 1024 + col];
    p.h[1] = (_Float16)U[(2 * k2 + 1) * 1024 + col];
    Uf[idx] = p.u;
}

// ---------------------------------------------------------------------------
// Generic f32 GEMM: C[M,N] = opA(A)[M,K] @ B[K,N] + bias[N]
// opA = optional row reversal (revA). 64x64 tile, 256 threads, 4x4 microtile.
// ---------------------------------------------------------------------------
__global__ __launch_bounds__(256) void gemm_bias(const float* __restrict__ A,
                                                 const float* __restrict__ B,
                                                 const float* __restrict__ bias,
                                                 float* __restrict__ C,
                                                 int M, int N, int K, int revA) {
    __shared__ float sA[16][65];
    __shared__ float sB[16][65];
    int tid = threadIdx.x;
    int bm = blockIdx.y * 64, bn = blockIdx.x * 64;
    int tx = tid & 15, ty = tid >> 4;
    float acc[4][4] = {};
    for (int k0 = 0; k0 < K; k0 += 16) {
#pragma unroll
        for (int l = 0; l < 4; l++) {
            int flat = tid + 256 * l;        // 0..1023 = 64 rows x 16 k
            int ml = flat >> 4, kk = flat & 15;
            int row = bm + ml;
            if (revA) row = M - 1 - row;
            sA[kk][ml] = A[row * K + k0 + kk];
        }
#pragma unroll
        for (int l = 0; l < 4; l++) {
            int flat = tid + 256 * l;        // 16 k x 64 n
            int kk = flat >> 6, nl = flat & 63;
            sB[kk][nl] = B[(k0 + kk) * N + bn + nl];
        }
        __syncthreads();
#pragma unroll
        for (int kk = 0; kk < 16; kk++) {
            float a[4], b[4];
#pragma unroll
            for (int i = 0; i < 4; i++) a[i] = sA[kk][ty + 16 * i];
#pragma unroll
            for (int j = 0; j < 4; j++) b[j] = sB[kk][tx + 16 * j];
#pragma unroll
            for (int i = 0; i < 4; i++)
#pragma unroll
                for (int j = 0; j < 4; j++) acc[i][j] += a[i] * b[j];
        }
        __syncthreads();
    }
#pragma unroll
    for (int i = 0; i < 4; i++) {
        int r = bm + ty + 16 * i;
#pragma unroll
        for (int j = 0; j < 4; j++) {
            int cidx = bn + tx + 16 * j;
            float bv = bias ? bias[cidx] : 0.f;
            C[r * N + cidx] = acc[i][j] + bv;
        }
    }
}

// ---------------------------------------------------------------------------
// lstm_two: 2 blocks (fwd, bwd), 512 threads each, 1 CU per block.
// U (f16 packed) resident: k2 in [0,36) in LDS (144KB), k2 in [36,128) in
// 184 VGPRs/thread (2 columns x 92 half2). h carried as f16 in LDS,
// c as f32 in registers of threads 0..255. P = pre-gates [512][1024] f32.
// Gate order i,f,g,o in the 1024 columns.
// __launch_bounds__(512, 1): cap = 256 VGPR/thread (1 block/CU). The
// previous (512, 2) capped at 128 VGPR -> the 184-reg U spilled to scratch
// (FETCH_SIZE 2.5 GB/dispatch, 2.7x slowdown).
// ---------------------------------------------------------------------------
#define KLDS 36
#define KREG 92

__global__ __launch_bounds__(512, 1) void lstm_two(
        const unsigned int* __restrict__ Ua, const unsigned int* __restrict__ Ub,
        const float* __restrict__ Pa, const float* __restrict__ Pb,
        float* __restrict__ Oa, float* __restrict__ Ob) {
    const unsigned int* U = blockIdx.x ? Ub : Ua;
    const float* P = blockIdx.x ? Pb : Pa;
    float* O = blockIdx.x ? Ob : Oa;

    __shared__ unsigned int sU[KLDS * 1024];        // 147456 B
    __shared__ __align__(16) _Float16 sH[256];      // 512 B
    __shared__ float sZ[1024];                      // 4096 B

    int t = threadIdx.x;  // 0..511, owns columns 2t and 2t+1

    // stage LDS-resident part of U
    for (int i = t; i < KLDS * 1024; i += 512) sU[i] = U[i];

    // register-resident part of U
    unsigned int ur0[KREG], ur1[KREG];
#pragma unroll
    for (int r = 0; r < KREG; r++) {
        ur0[r] = U[(KLDS + r) * 1024 + 2 * t];
        ur1[r] = U[(KLDS + r) * 1024 + 2 * t + 1];
    }

    float c = 0.f;
    if (t < 256) sH[t] = (_Float16)0.f;
    __syncthreads();

    float2 pc = *(const float2*)(P + 2 * t);
    for (int step = 0; step < 512; step++) {
        float2 pn = pc;
        if (step < 511) pn = *(const float2*)(P + (step + 1) * 1024 + 2 * t);
        // dual accumulators per column: break the 256-deep dependent
        // v_dot2 chain (4-cyc dep latency, only 2 waves/SIMD to cover it)
        float acc0a = pc.x, acc0b = 0.f, acc1a = pc.y, acc1b = 0.f;
        const h2v* hp = (const h2v*)sH;
#pragma unroll
        for (int k2 = 0; k2 < KLDS; k2 += 2) {
            h2v ha = hp[k2], hb = hp[k2 + 1];
            acc0a = fdot2f(ha, __builtin_bit_cast(h2v, sU[k2 * 1024 + 2 * t]), acc0a);
            acc1a = fdot2f(ha, __builtin_bit_cast(h2v, sU[k2 * 1024 + 2 * t + 1]), acc1a);
            acc0b = fdot2f(hb, __builtin_bit_cast(h2v, sU[(k2 + 1) * 1024 + 2 * t]), acc0b);
            acc1b = fdot2f(hb, __builtin_bit_cast(h2v, sU[(k2 + 1) * 1024 + 2 * t + 1]), acc1b);
        }
#pragma unroll
        for (int r = 0; r < KREG; r += 2) {
            h2v ha = hp[KLDS + r], hb = hp[KLDS + r + 1];
            acc0a = fdot2f(ha, __builtin_bit_cast(h2v, ur0[r]), acc0a);
            acc1a = fdot2f(ha, __builtin_bit_cast(h2v, ur1[r]), acc1a);
            acc0b = fdot2f(hb, __builtin_bit_cast(h2v, ur0[r + 1]), acc0b);
            acc1b = fdot2f(hb, __builtin_bit_cast(h2v, ur1[r + 1]), acc1b);
        }
        sZ[2 * t] = acc0a + acc0b;
        sZ[2 * t + 1] = acc1a + acc1b;
        __syncthreads();
        if (t < 256) {
            float zi = sZ[t], zf = sZ[256 + t], zg = sZ[512 + t], zo = sZ[768 + t];
            float ig = 1.f / (1.f + __expf(-zi));
            float fg = 1.f / (1.f + __expf(-zf));
            float gg = 1.f - 2.f / (1.f + __expf(2.f * zg));   // tanh
            float og = 1.f / (1.f + __expf(-zo));
            c = fg * c + ig * gg;
            float h = og * (1.f - 2.f / (1.f + __expf(2.f * c)));
            O[step * 256 + t] = h;
            sH[t] = (_Float16)h;
        }
        __syncthreads();
        pc = pn;
    }
}

// ---------------------------------------------------------------------------
// concat: V[t][0:256] = F[t], V[t][256:512] = Bk[511-t]
// ---------------------------------------------------------------------------
__global__ __launch_bounds__(256) void concat_k(const float* __restrict__ F,
                                                const float* __restrict__ Bk,
                                                float* __restrict__ V) {
    int idx = blockIdx.x * 256 + threadIdx.x;  // < 262144
    int t = idx >> 9, d = idx & 511;
    V[idx] = (d < 256) ? F[t * 256 + d] : Bk[(511 - t) * 256 + d - 256];
}

// ---------------------------------------------------------------------------
// head: S[i][j] = sum_h tanh(HF[i][h] + MF[j][h]) * w[h] + outBias
// (hidBias already folded into HF by its GEMM.)
// ---------------------------------------------------------------------------
__global__ __launch_bounds__(256) void head_kernel(const float* __restrict__ HF,
                                                   const float* __restrict__ MF,
                                                   const float* __restrict__ w,
                                                   const float* __restrict__ outb,
                                                   float* __restrict__ S) {
    int i = blockIdx.x;
    __shared__ float sHF[512], sW[512];
    int tid = threadIdx.x;
    sHF[tid] = HF[i * 512 + tid];
    sHF[tid + 256] = HF[i * 512 + 256 + tid];
    sW[tid] = w[tid];
    sW[tid + 256] = w[tid + 256];
    __syncthreads();
    int lane = tid & 63, wv = tid >> 6;
    float ob = outb[0];
    for (int j = wv; j < 512; j += 4) {
        const float* mf = MF + j * 512;
        float acc = 0.f;
#pragma unroll
        for (int r = 0; r < 8; r++) {
            int h = lane + 64 * r;
            float x = sHF[h] + mf[h];
            acc += sW[h] * (1.f - 2.f / (1.f + __expf(2.f * x)));
        }
#pragma unroll
        for (int off = 32; off; off >>= 1) acc += __shfl_down(acc, off);
        if (lane == 0) S[i * 512 + j] = acc + ob;
    }
}

// ---------------------------------------------------------------------------
extern "C" void kernel_launch(void* const* d_in, const int* in_sizes, int n_in,
                              void* d_out, int out_size, void* d_ws, size_t ws_size,
                              hipStream_t stream) {
    const float* emb      = (const float*)d_in[0];
    const float* W_f1     = (const float*)d_in[1];
    const float* U_f1     = (const float*)d_in[2];
    const float* b_f1     = (const float*)d_in[3];
    const float* W_b1     = (const float*)d_in[4];
    const float* U_b1     = (const float*)d_in[5];
    const float* b_b1     = (const float*)d_in[6];
    const float* W_f2     = (const float*)d_in[7];
    const float* U_f2     = (const float*)d_in[8];
    const float* b_f2     = (const float*)d_in[9];
    const float* W_b2     = (const float*)d_in[10];
    const float* U_b2     = (const float*)d_in[11];
    const float* b_b2     = (const float*)d_in[12];
    const float* FOH      = (const float*)d_in[13];
    const float* FOM      = (const float*)d_in[14];
    const float* hidBias  = (const float*)d_in[15];
    const float* outLayer = (const float*)d_in[16];
    const float* outBias  = (const float*)d_in[17];
    float* out = (float*)d_out;

    // workspace carve (16 MB total)
    unsigned int* uf = (unsigned int*)d_ws;          // 4 x 131072 uints = 2MB
    unsigned int* uf_f1 = uf;
    unsigned int* uf_b1 = uf + 131072;
    unsigned int* uf_f2 = uf + 262144;
    unsigned int* uf_b2 = uf + 393216;
    float* f = (float*)d_ws + 524288;
    float* P1f = f;                 // 512x1024
    float* P1b = f + 524288;
    float* P2f = f + 1048576;
    float* P2b = f + 1572864;
    float* rf1 = f + 2097152;       // 512x256
    float* rb1 = f + 2228224;
    float* rf2 = f + 2359296;
    float* rb2 = f + 2490368;
    float* v    = f + 2621440;      // 512x512
    float* hcat = f + 2883584;
    float* HFb  = f + 3145728;      // 512x512 (includes hidBias)
    float* MFb  = f + 3407872;

    prep_u<<<512, 256, 0, stream>>>(U_f1, uf_f1);
    prep_u<<<512, 256, 0, stream>>>(U_b1, uf_b1);
    prep_u<<<512, 256, 0, stream>>>(U_f2, uf_f2);
    prep_u<<<512, 256, 0, stream>>>(U_b2, uf_b2);

    dim3 g1(1024 / 64, 512 / 64);
    gemm_bias<<<g1, 256, 0, stream>>>(emb, W_f1, b_f1, P1f, 512, 1024, 256, 0);
    gemm_bias<<<g1, 256, 0, stream>>>(emb, W_b1, b_b1, P1b, 512, 1024, 256, 1);

    lstm_two<<<2, 512, 0, stream>>>(uf_f1, uf_b1, P1f, P1b, rf1, rb1);

    concat_k<<<1024, 256, 0, stream>>>(rf1, rb1, v);

    gemm_bias<<<g1, 256, 0, stream>>>(v, W_f2, b_f2, P2f, 512, 1024, 512, 0);
    gemm_bias<<<g1, 256, 0, stream>>>(v, W_b2, b_b2, P2b, 512, 1024, 512, 1);

    lstm_two<<<2, 512, 0, stream>>>(uf_f2, uf_b2, P2f, P2b, rf2, rb2);

    concat_k<<<1024, 256, 0, stream>>>(rf2, rb2, hcat);

    dim3 g2(512 / 64, 512 / 64);
    gemm_bias<<<g2, 256, 0, stream>>>(hcat, FOH, hidBias, HFb, 512, 512, 512, 0);
    gemm_bias<<<g2, 256, 0, stream>>>(hcat, FOM, nullptr, MFb, 512, 512, 512, 0);

    head_kernel<<<512, 256, 0, stream>>>(HFb, MFb, outLayer, outBias, out);
}

// Round 3
// 2745.903 us; speedup vs baseline: 1.0344x; 1.0259x over previous
//
#include <hip/hip_runtime.h>
#include <hip/hip_bf16.h>

// Sizes (fixed): T=512 tokens, D=256 embed, L=256 lstm, H=512 hidden. 4L=1024.

typedef _Float16 h2v __attribute__((ext_vector_type(2)));
typedef unsigned int u32x32 __attribute__((ext_vector_type(32)));

#define BC(x) __builtin_bit_cast(h2v, (x))

__device__ __forceinline__ float fdot2f(h2v a, h2v b, float c) {
#if __has_builtin(__builtin_amdgcn_fdot2)
    return __builtin_amdgcn_fdot2(a, b, c, false);
#else
    return c + (float)a[0] * (float)b[0] + (float)a[1] * (float)b[1];
#endif
}

// ---------------------------------------------------------------------------
// prep_u: U [256 x 1024] f32 row-major -> packed half2 per (k-pair, col)
// Uf[k2*1024 + col] = (U[2k2][col], U[2k2+1][col]) as 2xf16 in a uint
// ---------------------------------------------------------------------------
__global__ __launch_bounds__(256) void prep_u(const float* __restrict__ U,
                                              unsigned int* __restrict__ Uf) {
    int idx = blockIdx.x * 256 + threadIdx.x;  // < 131072
    int k2 = idx >> 10, col = idx & 1023;
    union { _Float16 h[2]; unsigned int u; } p;
    p.h[0] = (_Float16)U[(2 * k2) * 1024 + col];
    p.h[1] = (_Float16)U[(2 * k2 + 1) * 1024 + col];
    Uf[idx] = p.u;
}

// ---------------------------------------------------------------------------
// Generic f32 GEMM: C[M,N] = opA(A)[M,K] @ B[K,N] + bias[N]
// ---------------------------------------------------------------------------
__global__ __launch_bounds__(256) void gemm_bias(const float* __restrict__ A,
                                                 const float* __restrict__ B,
                                                 const float* __restrict__ bias,
                                                 float* __restrict__ C,
                                                 int M, int N, int K, int revA) {
    __shared__ float sA[16][65];
    __shared__ float sB[16][65];
    int tid = threadIdx.x;
    int bm = blockIdx.y * 64, bn = blockIdx.x * 64;
    int tx = tid & 15, ty = tid >> 4;
    float acc[4][4] = {};
    for (int k0 = 0; k0 < K; k0 += 16) {
#pragma unroll
        for (int l = 0; l < 4; l++) {
            int flat = tid + 256 * l;
            int ml = flat >> 4, kk = flat & 15;
            int row = bm + ml;
            if (revA) row = M - 1 - row;
            sA[kk][ml] = A[row * K + k0 + kk];
        }
#pragma unroll
        for (int l = 0; l < 4; l++) {
            int flat = tid + 256 * l;
            int kk = flat >> 6, nl = flat & 63;
            sB[kk][nl] = B[(k0 + kk) * N + bn + nl];
        }
        __syncthreads();
#pragma unroll
        for (int kk = 0; kk < 16; kk++) {
            float a[4], b[4];
#pragma unroll
            for (int i = 0; i < 4; i++) a[i] = sA[kk][ty + 16 * i];
#pragma unroll
            for (int j = 0; j < 4; j++) b[j] = sB[kk][tx + 16 * j];
#pragma unroll
            for (int i = 0; i < 4; i++)
#pragma unroll
                for (int j = 0; j < 4; j++) acc[i][j] += a[i] * b[j];
        }
        __syncthreads();
    }
#pragma unroll
    for (int i = 0; i < 4; i++) {
        int r = bm + ty + 16 * i;
#pragma unroll
        for (int j = 0; j < 4; j++) {
            int cidx = bn + tx + 16 * j;
            float bv = bias ? bias[cidx] : 0.f;
            C[r * N + cidx] = acc[i][j] + bv;
        }
    }
}

// ---------------------------------------------------------------------------
// lstm_two: 2 blocks (fwd, bwd), 512 threads, 1 block/CU.
// U (f16 packed, 512KB/dir) fully on-chip: rows [0,32) in LDS (128KB),
// rows [32,128) in SSA ext-vectors (6 x 32 uints = 192 VGPR/thread; thread t
// owns columns 2t, 2t+1). amdgpu_waves_per_eu(2,2) pins the allocator budget
// to 256 VGPR/wave (2 waves/SIMD x 256 = 512-reg file). Round-1/2 failure:
// C-array U -> alloca -> backend targeted 4 waves/EU (128 VGPR) and spilled
// the whole array to scratch (FETCH 2.5GB/dispatch, 1200us). Vector SSA
// values + pinned occupancy range remove both causes.
// ---------------------------------------------------------------------------
#define KLDS 32
#define KREG 96

// constant-index select across the three 32-wide vectors; folds at -O3
#define UR0(r) ((r) < 32 ? u0a[(r) & 31] : (r) < 64 ? u0b[(r) & 31] : u0c[(r) & 31])
#define UR1(r) ((r) < 32 ? u1a[(r) & 31] : (r) < 64 ? u1b[(r) & 31] : u1c[(r) & 31])

__global__ __attribute__((amdgpu_flat_work_group_size(512, 512),
                          amdgpu_waves_per_eu(2, 2)))
void lstm_two(
        const unsigned int* __restrict__ Ua, const unsigned int* __restrict__ Ub,
        const float* __restrict__ Pa, const float* __restrict__ Pb,
        float* __restrict__ Oa, float* __restrict__ Ob) {
    const unsigned int* U = blockIdx.x ? Ub : Ua;
    const float* P = blockIdx.x ? Pb : Pa;
    float* O = blockIdx.x ? Ob : Oa;

    __shared__ unsigned int sU[KLDS * 1024];        // 131072 B
    __shared__ __align__(16) _Float16 sH[256];      // 512 B
    __shared__ float sZ[1024];                      // 4096 B

    int t = threadIdx.x;  // 0..511, owns columns 2t and 2t+1

    // stage LDS-resident rows of U
    for (int i = t; i < KLDS * 1024; i += 512) sU[i] = U[i];

    // register-resident rows of U as SSA vector values (no alloca)
    u32x32 u0a, u0b, u0c, u1a, u1b, u1c;
#pragma unroll
    for (int r = 0; r < 32; r++) {
        uint2 w;
        w = *(const uint2*)&U[(KLDS + r) * 1024 + 2 * t];
        u0a[r] = w.x; u1a[r] = w.y;
        w = *(const uint2*)&U[(KLDS + 32 + r) * 1024 + 2 * t];
        u0b[r] = w.x; u1b[r] = w.y;
        w = *(const uint2*)&U[(KLDS + 64 + r) * 1024 + 2 * t];
        u0c[r] = w.x; u1c[r] = w.y;
    }

    float c = 0.f;
    if (t < 256) sH[t] = (_Float16)0.f;
    __syncthreads();

    const uint4* hp4 = (const uint4*)sH;  // 32 chunks x (4 h2v) = 256 h
    float2 pc = *(const float2*)(P + 2 * t);
    for (int step = 0; step < 512; step++) {
        float2 pn = pc;
        if (step < 511) pn = *(const float2*)(P + (step + 1) * 1024 + 2 * t);
        float acc0 = pc.x, acc1 = pc.y;  // two cols = two indep dep-chains

        // rows 0..31 from LDS: h via b128 broadcast, U via b64 (2-way=free)
#pragma unroll
        for (int cch = 0; cch < 8; cch++) {
            uint4 hc = hp4[cch];
            const unsigned int* su = &sU[(4 * cch) * 1024 + 2 * t];
            uint2 w;
            w = *(const uint2*)(su);
            acc0 = fdot2f(BC(hc.x), BC(w.x), acc0);
            acc1 = fdot2f(BC(hc.x), BC(w.y), acc1);
            w = *(const uint2*)(su + 1024);
            acc0 = fdot2f(BC(hc.y), BC(w.x), acc0);
            acc1 = fdot2f(BC(hc.y), BC(w.y), acc1);
            w = *(const uint2*)(su + 2048);
            acc0 = fdot2f(BC(hc.z), BC(w.x), acc0);
            acc1 = fdot2f(BC(hc.z), BC(w.y), acc1);
            w = *(const uint2*)(su + 3072);
            acc0 = fdot2f(BC(hc.w), BC(w.x), acc0);
            acc1 = fdot2f(BC(hc.w), BC(w.y), acc1);
        }
        // rows 32..127 from registers
#pragma unroll
        for (int cch = 0; cch < 24; cch++) {
            uint4 hc = hp4[8 + cch];
            const int r0 = 4 * cch;
            acc0 = fdot2f(BC(hc.x), BC(UR0(r0 + 0)), acc0);
            acc1 = fdot2f(BC(hc.x), BC(UR1(r0 + 0)), acc1);
            acc0 = fdot2f(BC(hc.y), BC(UR0(r0 + 1)), acc0);
            acc1 = fdot2f(BC(hc.y), BC(UR1(r0 + 1)), acc1);
            acc0 = fdot2f(BC(hc.z), BC(UR0(r0 + 2)), acc0);
            acc1 = fdot2f(BC(hc.z), BC(UR1(r0 + 2)), acc1);
            acc0 = fdot2f(BC(hc.w), BC(UR0(r0 + 3)), acc0);
            acc1 = fdot2f(BC(hc.w), BC(UR1(r0 + 3)), acc1);
        }
        ((float2*)sZ)[t] = make_float2(acc0, acc1);
        __syncthreads();
        if (t < 256) {
            float zi = sZ[t], zf = sZ[256 + t], zg = sZ[512 + t], zo = sZ[768 + t];
            float ig = 1.f / (1.f + __expf(-zi));
            float fg = 1.f / (1.f + __expf(-zf));
            float gg = 1.f - 2.f / (1.f + __expf(2.f * zg));   // tanh
            float og = 1.f / (1.f + __expf(-zo));
            c = fg * c + ig * gg;
            float h = og * (1.f - 2.f / (1.f + __expf(2.f * c)));
            O[step * 256 + t] = h;
            sH[t] = (_Float16)h;
        }
        __syncthreads();
        pc = pn;
    }
}

// ---------------------------------------------------------------------------
// concat: V[t][0:256] = F[t], V[t][256:512] = Bk[511-t]
// ---------------------------------------------------------------------------
__global__ __launch_bounds__(256) void concat_k(const float* __restrict__ F,
                                                const float* __restrict__ Bk,
                                                float* __restrict__ V) {
    int idx = blockIdx.x * 256 + threadIdx.x;  // < 262144
    int t = idx >> 9, d = idx & 511;
    V[idx] = (d < 256) ? F[t * 256 + d] : Bk[(511 - t) * 256 + d - 256];
}

// ---------------------------------------------------------------------------
// head: S[i][j] = sum_h tanh(HF[i][h] + MF[j][h]) * w[h] + outBias
// ---------------------------------------------------------------------------
__global__ __launch_bounds__(256) void head_kernel(const float* __restrict__ HF,
                                                   const float* __restrict__ MF,
                                                   const float* __restrict__ w,
                                                   const float* __restrict__ outb,
                                                   float* __restrict__ S) {
    int i = blockIdx.x;
    __shared__ float sHF[512], sW[512];
    int tid = threadIdx.x;
    sHF[tid] = HF[i * 512 + tid];
    sHF[tid + 256] = HF[i * 512 + 256 + tid];
    sW[tid] = w[tid];
    sW[tid + 256] = w[tid + 256];
    __syncthreads();
    int lane = tid & 63, wv = tid >> 6;
    float ob = outb[0];
    for (int j = wv; j < 512; j += 4) {
        const float* mf = MF + j * 512;
        float acc = 0.f;
#pragma unroll
        for (int r = 0; r < 8; r++) {
            int h = lane + 64 * r;
            float x = sHF[h] + mf[h];
            acc += sW[h] * (1.f - 2.f / (1.f + __expf(2.f * x)));
        }
#pragma unroll
        for (int off = 32; off; off >>= 1) acc += __shfl_down(acc, off);
        if (lane == 0) S[i * 512 + j] = acc + ob;
    }
}

// ---------------------------------------------------------------------------
extern "C" void kernel_launch(void* const* d_in, const int* in_sizes, int n_in,
                              void* d_out, int out_size, void* d_ws, size_t ws_size,
                              hipStream_t stream) {
    const float* emb      = (const float*)d_in[0];
    const float* W_f1     = (const float*)d_in[1];
    const float* U_f1     = (const float*)d_in[2];
    const float* b_f1     = (const float*)d_in[3];
    const float* W_b1     = (const float*)d_in[4];
    const float* U_b1     = (const float*)d_in[5];
    const float* b_b1     = (const float*)d_in[6];
    const float* W_f2     = (const float*)d_in[7];
    const float* U_f2     = (const float*)d_in[8];
    const float* b_f2     = (const float*)d_in[9];
    const float* W_b2     = (const float*)d_in[10];
    const float* U_b2     = (const float*)d_in[11];
    const float* b_b2     = (const float*)d_in[12];
    const float* FOH      = (const float*)d_in[13];
    const float* FOM      = (const float*)d_in[14];
    const float* hidBias  = (const float*)d_in[15];
    const float* outLayer = (const float*)d_in[16];
    const float* outBias  = (const float*)d_in[17];
    float* out = (float*)d_out;

    // workspace carve (16 MB total)
    unsigned int* uf = (unsigned int*)d_ws;          // 4 x 131072 uints = 2MB
    unsigned int* uf_f1 = uf;
    unsigned int* uf_b1 = uf + 131072;
    unsigned int* uf_f2 = uf + 262144;
    unsigned int* uf_b2 = uf + 393216;
    float* f = (float*)d_ws + 524288;
    float* P1f = f;                 // 512x1024
    float* P1b = f + 524288;
    float* P2f = f + 1048576;
    float* P2b = f + 1572864;
    float* rf1 = f + 2097152;       // 512x256
    float* rb1 = f + 2228224;
    float* rf2 = f + 2359296;
    float* rb2 = f + 2490368;
    float* v    = f + 2621440;      // 512x512
    float* hcat = f + 2883584;
    float* HFb  = f + 3145728;      // 512x512 (includes hidBias)
    float* MFb  = f + 3407872;

    prep_u<<<512, 256, 0, stream>>>(U_f1, uf_f1);
    prep_u<<<512, 256, 0, stream>>>(U_b1, uf_b1);
    prep_u<<<512, 256, 0, stream>>>(U_f2, uf_f2);
    prep_u<<<512, 256, 0, stream>>>(U_b2, uf_b2);

    dim3 g1(1024 / 64, 512 / 64);
    gemm_bias<<<g1, 256, 0, stream>>>(emb, W_f1, b_f1, P1f, 512, 1024, 256, 0);
    gemm_bias<<<g1, 256, 0, stream>>>(emb, W_b1, b_b1, P1b, 512, 1024, 256, 1);

    lstm_two<<<2, 512, 0, stream>>>(uf_f1, uf_b1, P1f, P1b, rf1, rb1);

    concat_k<<<1024, 256, 0, stream>>>(rf1, rb1, v);

    gemm_bias<<<g1, 256, 0, stream>>>(v, W_f2, b_f2, P2f, 512, 1024, 512, 0);
    gemm_bias<<<g1, 256, 0, stream>>>(v, W_b2, b_b2, P2b, 512, 1024, 512, 1);

    lstm_two<<<2, 512, 0, stream>>>(uf_f2, uf_b2, P2f, P2b, rf2, rb2);

    concat_k<<<1024, 256, 0, stream>>>(rf2, rb2, hcat);

    dim3 g2(512 / 64, 512 / 64);
    gemm_bias<<<g2, 256, 0, stream>>>(hcat, FOH, hidBias, HFb, 512, 512, 512, 0);
    gemm_bias<<<g2, 256, 0, stream>>>(hcat, FOM, nullptr, MFb, 512, 512, 512, 0);

    head_kernel<<<512, 256, 0, stream>>>(HFb, MFb, outLayer, outBias, out);
}